// Round 4
// baseline (184.539 us; speedup 1.0000x reference)
//
#include <hip/hip_runtime.h>
#include <stdint.h>
#include <stddef.h>
#include <algorithm>

// Problem constants (fixed by the reference file)
#define BATCH  1024
#define S1     25
#define S2     10
#define DIM    256
#define NNEIB  64
#define L2ROWS (BATCH * S1)          // 25600
#define MROWS  (BATCH + BATCH * S1)  // 26624 (multiple of 128)
#define KTOT   512                   // GEMM K = [X | M]
#define NFEAT  50000

struct Perm25 { int p[S1]; };
struct Perm10 { int p[S2]; };

typedef __attribute__((ext_vector_type(8))) short short8;
typedef __attribute__((ext_vector_type(4))) float f32x4;

// ======================= host-side JAX threefry replication ==================
static inline uint32_t rotl_(uint32_t x, int d) { return (x << d) | (x >> (32 - d)); }

static void tf2x32(uint32_t k0, uint32_t k1, uint32_t x0, uint32_t x1,
                   uint32_t* o0, uint32_t* o1) {
  const uint32_t ks0 = k0, ks1 = k1, ks2 = k0 ^ k1 ^ 0x1BD11BDAu;
  static const int R[8] = {13, 15, 26, 6, 17, 29, 16, 24};
  x0 += ks0; x1 += ks1;
  for (int g = 0; g < 5; ++g) {
    const int* rr = R + (g & 1) * 4;
    for (int i = 0; i < 4; i++) { x0 += x1; x1 = rotl_(x1, rr[i]); x1 ^= x0; }
    uint32_t a, b;
    switch (g) {
      default:
      case 0: a = ks1; b = ks2; break;
      case 1: a = ks2; b = ks0; break;
      case 2: a = ks0; b = ks1; break;
      case 3: a = ks1; b = ks2; break;
      case 4: a = ks2; b = ks0; break;
    }
    x0 += a; x1 = x1 + b + (uint32_t)(g + 1);
  }
  *o0 = x0; *o1 = x1;
}

// jax.random.permutation(fold_in(key(42), li), 64), partitionable threefry
// (verified correct in earlier rounds).
static void compute_perm(uint32_t li, int n, int* out) {
  uint32_t k0, k1, s0, s1;
  tf2x32(0u, 42u, 0u, li, &k0, &k1);
  tf2x32(k0, k1, 0u, 1u, &s0, &s1);
  uint32_t bits[NNEIB];
  for (int i = 0; i < NNEIB; i++) {
    uint32_t a, b;
    tf2x32(s0, s1, 0u, (uint32_t)i, &a, &b);
    bits[i] = a ^ b;
  }
  int idx[NNEIB];
  for (int i = 0; i < NNEIB; i++) idx[i] = i;
  std::stable_sort(idx, idx + NNEIB, [&](int A, int B) { return bits[A] < bits[B]; });
  for (int j = 0; j < n; j++) out[j] = idx[j];
}

// ============================ device helpers =================================
__device__ __forceinline__ unsigned short f2bf(float x) {
  union { float f; uint32_t u; } v; v.f = x;
  uint32_t r = (v.u + 0x7FFFu + ((v.u >> 16) & 1u)) >> 16;   // RNE
  return (unsigned short)r;
}
__device__ __forceinline__ float bfbits2f(uint32_t lo16) {
  union { uint32_t u; float f; } v; v.u = lo16 << 16;
  return v.f;
}
// async global->LDS, 16 B per lane. GLOBAL source address is PER-LANE
// (m104/m108) -> gathers/pre-swizzles are fine; LDS dest is wave-uniform
// base + lane*16 -> LDS layout must be linear (rule #21).
__device__ __forceinline__ void gload16(const unsigned short* g, unsigned short* l) {
  __builtin_amdgcn_global_load_lds(
      (const __attribute__((address_space(1))) unsigned int*)g,
      (__attribute__((address_space(3))) unsigned int*)l, 16, 0, 0);
}

// ================================ kernels ====================================

// Fused prep: [0,12500) convf  |  [12500,13012) convw W1 | [13012,13524) convw W2
// | [13524,13528) sample1. All partitions independent.
#define PREP_CONVF   12500   // NFEAT*DIM/4/256
#define PREP_CONVW   512     // DIM*KTOT/256
#define PREP_BLOCKS  (PREP_CONVF + 2 * PREP_CONVW + 4)
__global__ __launch_bounds__(256) void prep_k(
    const float* __restrict__ feats, uint32_t* __restrict__ fb,
    const float* __restrict__ Wx1, const float* __restrict__ Wn1,
    unsigned short* __restrict__ Wt1,
    const float* __restrict__ Wx2, const float* __restrict__ Wn2,
    unsigned short* __restrict__ Wt2,
    const int* __restrict__ ids, const int* __restrict__ dix,
    const float* __restrict__ dval, int* __restrict__ idx1,
    float* __restrict__ w1, Perm25 pm) {
  int b = blockIdx.x, t = threadIdx.x;
  if (b < PREP_CONVF) {
    // feats fp32 -> packed bf16, 4 elem/thread, one 8 B store
    int i = b * 256 + t;
    f32x4 v = *(const f32x4*)&feats[(size_t)i * 4];
    uint2 o;
    o.x = f2bf(v.x) | ((uint32_t)f2bf(v.y) << 16);
    o.y = f2bf(v.z) | ((uint32_t)f2bf(v.w) << 16);
    ((uint2*)fb)[i] = o;
  } else if (b < PREP_CONVF + 2 * PREP_CONVW) {
    int wi = b - PREP_CONVF;
    const float* Wx = (wi < PREP_CONVW) ? Wx1 : Wx2;
    const float* Wn = (wi < PREP_CONVW) ? Wn1 : Wn2;
    unsigned short* Wt = (wi < PREP_CONVW) ? Wt1 : Wt2;
    int idx = (wi % PREP_CONVW) * 256 + t;
    int n = idx >> 9, k = idx & 511;
    float v = (k < DIM) ? Wx[(size_t)k * DIM + n] : Wn[(size_t)(k - DIM) * DIM + n];
    Wt[(size_t)n * KTOT + k] = f2bf(v);
  } else {
    // sample1: layer-0 neighbor sampling for the 1024 batch nodes
    int i = (b - PREP_CONVF - 2 * PREP_CONVW) * 256 + t;
    if (i >= BATCH) return;
    int nid = ids[i];
    const float* vr = dval + (size_t)nid * NNEIB;
    const int* ir = dix + (size_t)nid * NNEIB;
    float v[S1];
    float s = 0.f;
    for (int j = 0; j < S1; j++) { v[j] = vr[pm.p[j]]; s += v[j]; }
    float inv = 1.f / (s + 1e-10f);
    for (int j = 0; j < S1; j++) {
      w1[i * S1 + j] = v[j] * inv;
      idx1[i * S1 + j] = ir[pm.p[j]];
    }
  }
}

// Weighted-mean aggregation, 2 rows per load instruction: half-wave h=lane>>5
// takes rows 2p+h; each half-lane gathers 16 B (8 bf16 cols). Even/odd
// partials combined by shfl_xor(32) at the end (f32 re-association only).
template <int S>
__device__ __forceinline__ void agg_pairs(const uint4* __restrict__ fb, int nbl,
                                          float wl, int lane, float a[8]) {
  int h = lane >> 5, l5 = lane & 31;
#pragma unroll
  for (int p = 0; p < (S + 1) / 2; p++) {
    int jj = 2 * p + h;
    int nid = __shfl(nbl, (jj < S) ? jj : 0);
    float wj = (jj < S) ? __shfl(wl, jj) : 0.f;
    uint4 u = fb[(size_t)nid * 32 + l5];
    a[0] += wj * bfbits2f(u.x & 0xffffu); a[1] += wj * bfbits2f(u.x >> 16);
    a[2] += wj * bfbits2f(u.y & 0xffffu); a[3] += wj * bfbits2f(u.y >> 16);
    a[4] += wj * bfbits2f(u.z & 0xffffu); a[5] += wj * bfbits2f(u.z >> 16);
    a[6] += wj * bfbits2f(u.w & 0xffffu); a[7] += wj * bfbits2f(u.w >> 16);
  }
}

// stage1: M1[r] = weighted mean of bf16 neighbor rows (M-half ONLY; gemm1
// gathers the X-half itself via per-lane global_load_lds addresses).
// Wave-per-row, 4 rows/block, uint4 paired gathers.
__global__ __launch_bounds__(256) void stage1_k(
    const uint4* __restrict__ fb, const int* __restrict__ idx1,
    const float* __restrict__ w1, const int* __restrict__ dix,
    const float* __restrict__ dval, Perm10 pm2, uint4* __restrict__ M1) {
  int wave = threadIdx.x >> 6, lane = threadIdx.x & 63;
  int r = blockIdx.x * 4 + wave;
  float a[8] = {0.f, 0.f, 0.f, 0.f, 0.f, 0.f, 0.f, 0.f};
  if (r < BATCH) {
    int nbl = 0; float wl = 0.f;
    if (lane < S1) { nbl = idx1[r * S1 + lane]; wl = w1[r * S1 + lane]; }
    agg_pairs<S1>(fb, nbl, wl, lane, a);
  } else {
    int nx = idx1[r - BATCH];
    int nbl = 0; float vj = 0.f;
    if (lane < S2) {
      int c = pm2.p[lane];
      nbl = dix[(size_t)nx * NNEIB + c];
      vj = dval[(size_t)nx * NNEIB + c];
    }
    float tot = 0.f;
#pragma unroll
    for (int j = 0; j < S2; j++) tot += __shfl(vj, j);
    float wl = vj / (tot + 1e-10f);
    agg_pairs<S2>(fb, nbl, wl, lane, a);
  }
#pragma unroll
  for (int q = 0; q < 8; q++) a[q] += __shfl_xor(a[q], 32);
  if (lane < 32) {
    uint4 o;
    o.x = f2bf(a[0]) | ((uint32_t)f2bf(a[1]) << 16);
    o.y = f2bf(a[2]) | ((uint32_t)f2bf(a[3]) << 16);
    o.z = f2bf(a[4]) | ((uint32_t)f2bf(a[5]) << 16);
    o.w = f2bf(a[6]) | ((uint32_t)f2bf(a[7]) << 16);
    M1[(size_t)r * 32 + (lane & 31)] = o;
  }
}

// stage2: M2[i] = wmean over H rows 1024+i*25+j with w1 (M-half only; gemm2
// reads its X-half straight from Hb rows 0..1023). Wave-per-row.
__global__ __launch_bounds__(256) void stage2_k(
    const uint2* __restrict__ Hb, const float* __restrict__ w1,
    uint2* __restrict__ M2) {
  int wave = threadIdx.x >> 6, lane = threadIdx.x & 63;
  int i = blockIdx.x * 4 + wave;
  float wl = (lane < S1) ? w1[(size_t)i * S1 + lane] : 0.f;
  const uint2* hb = Hb + (size_t)(BATCH + i * S1) * 64 + lane;
  float a0 = 0.f, a1 = 0.f, a2 = 0.f, a3 = 0.f;
#pragma unroll
  for (int j = 0; j < S1; j++) {
    float wj = __shfl(wl, j);
    uint2 u = hb[(size_t)j * 64];
    a0 += wj * bfbits2f(u.x & 0xffffu);
    a1 += wj * bfbits2f(u.x >> 16);
    a2 += wj * bfbits2f(u.y & 0xffffu);
    a3 += wj * bfbits2f(u.y >> 16);
  }
  uint2 o;
  o.x = f2bf(a0) | ((uint32_t)f2bf(a1) << 16);
  o.y = f2bf(a2) | ((uint32_t)f2bf(a3) << 16);
  M2[(size_t)i * 64 + lane] = o;
}

// Unified MFMA GEMM, 64x128 tile, BK=64, DOUBLE-BUFFERED 2-phase pipeline
// (T3 minimum recipe): STAGE(k+1) issued BEFORE compute(k); ONE barrier per
// K-step; the __syncthreads' vmcnt(0) drains next-step loads only after this
// step's 24 ds_reads + 16 MFMAs have covered their latency.
// Virtual A row r = [ Ax[xrow(r)] | Am[r] ]; GATHER selects xrow via
// ids/idx1 (gemm1) or identity (gemm2). XOR chunk swizzle via pre-swizzled
// per-lane GLOBAL source + swizzled fragment read (LDS dest linear, rule
// #21). K accumulation ascending 32-windows -> bit-identical numerics.
template <bool GATHER, bool OUT_BF16>
__global__ __launch_bounds__(256, 4) void gemm_k(
    const unsigned short* __restrict__ Ax, const int* __restrict__ ids,
    const int* __restrict__ idx1, const unsigned short* __restrict__ Am,
    const unsigned short* __restrict__ Wt, const float* __restrict__ bx,
    const float* __restrict__ bn, void* __restrict__ OutP) {
  __shared__ __align__(16) unsigned short As[2][64][64];    // 16 KB
  __shared__ __align__(16) unsigned short Bs[2][128][64];   // 32 KB
  int t = threadIdx.x;
  int wave = t >> 6, lane = t & 63, quad = lane >> 4, l16 = lane & 15;
  int wm = (wave >> 1) * 32;   // 2x2 wave grid: 32-row halves
  int wn = (wave & 1) * 64;    // 64-col halves
  int row0 = blockIdx.x * 64, col0 = blockIdx.y * 128;

  f32x4 acc[2][4];
#pragma unroll
  for (int i = 0; i < 2; i++)
#pragma unroll
    for (int j = 0; j < 4; j++) acc[i][j] = (f32x4){0.f, 0.f, 0.f, 0.f};

  // staging: one gload16 = 8 rows x 64 cols (1024 B). lane l -> row l>>3,
  // 16B chunk (l&7). Source pre-swizzled: LDS pos (r,q) holds global chunk
  // q ^ (r&7) (XOR involution).
  int lrow = lane >> 3;
  int scol = (((lane & 7) ^ (lrow & 7)) << 3);   // swizzled source col (bf16)

  const unsigned short* xsA[2];
  const unsigned short* msA[2];   // pre-biased by -DIM so +k0 works
#pragma unroll
  for (int cc = 0; cc < 2; cc++) {
    int grow = row0 + (wave * 2 + cc) * 8 + lrow;
    int xr = GATHER ? ((grow < BATCH) ? ids[grow] : idx1[grow - BATCH]) : grow;
    xsA[cc] = Ax + (size_t)xr * DIM + scol;
    msA[cc] = Am + (size_t)grow * DIM + scol - DIM;
  }
  const unsigned short* bsrc[4];
#pragma unroll
  for (int cc = 0; cc < 4; cc++) {
    int brow = col0 + (wave * 4 + cc) * 8 + lrow;
    bsrc[cc] = Wt + (size_t)brow * KTOT + scol;
  }

  auto stage = [&](int buf, int k0) {
#pragma unroll
    for (int cc = 0; cc < 2; cc++)
      gload16(((k0 < DIM) ? xsA[cc] : msA[cc]) + k0, &As[buf][(wave * 2 + cc) * 8][0]);
#pragma unroll
    for (int cc = 0; cc < 4; cc++)
      gload16(bsrc[cc] + k0, &Bs[buf][(wave * 4 + cc) * 8][0]);
  };

  stage(0, 0);
  __syncthreads();   // vmcnt(0): buf0 resident

  int cur = 0;
  for (int k0 = 0; k0 < KTOT; k0 += 64, cur ^= 1) {
    if (k0 + 64 < KTOT) stage(cur ^ 1, k0 + 64);   // prefetch next K-step

    short8 af[2][2], bf8[4][2];
#pragma unroll
    for (int i = 0; i < 2; i++)
#pragma unroll
      for (int kk = 0; kk < 2; kk++)
        af[i][kk] = *(const short8*)
            &As[cur][wm + i * 16 + l16][(((kk << 2) + quad) ^ (l16 & 7)) << 3];
#pragma unroll
    for (int j = 0; j < 4; j++)
#pragma unroll
      for (int kk = 0; kk < 2; kk++)
        bf8[j][kk] = *(const short8*)
            &Bs[cur][wn + j * 16 + l16][(((kk << 2) + quad) ^ (l16 & 7)) << 3];
#pragma unroll
    for (int i = 0; i < 2; i++)
#pragma unroll
      for (int j = 0; j < 4; j++)
#pragma unroll
        for (int kk = 0; kk < 2; kk++)   // kk innermost: ascending-k order
          acc[i][j] = __builtin_amdgcn_mfma_f32_16x16x32_bf16(
              af[i][kk], bf8[j][kk], acc[i][j], 0, 0, 0);

    __syncthreads();   // one barrier/step: drains prefetch, releases buffers
  }

  // Epilogue: bias + relu. D layout: col = l16, row = quad*4 + reg (m89/m91).
  float bias[4];
#pragma unroll
  for (int j = 0; j < 4; j++) {
    int c = col0 + wn + j * 16 + l16;
    bias[j] = bx[c] + bn[c];
  }
#pragma unroll
  for (int i = 0; i < 2; i++) {
#pragma unroll
    for (int j = 0; j < 4; j++) {
      int c = col0 + wn + j * 16 + l16;
#pragma unroll
      for (int reg = 0; reg < 4; reg++) {
        int r = row0 + wm + i * 16 + quad * 4 + reg;
        float v = fmaxf(acc[i][j][reg] + bias[j], 0.f);
        if (OUT_BF16)
          ((unsigned short*)OutP)[(size_t)r * DIM + c] = f2bf(v);
        else
          ((float*)OutP)[(size_t)r * DIM + c] = v;
      }
    }
  }
}

// ================================ launcher ===================================
static inline size_t align256(size_t x) { return (x + 255) & ~(size_t)255; }

extern "C" void kernel_launch(void* const* d_in, const int* in_sizes, int n_in,
                              void* d_out, int out_size, void* d_ws, size_t ws_size,
                              hipStream_t stream) {
  const int*   ids  = (const int*)d_in[0];
  const int*   dix  = (const int*)d_in[1];
  const float* dval = (const float*)d_in[2];
  const float* feats= (const float*)d_in[3];
  const float* Wx1  = (const float*)d_in[4];
  const float* bx1  = (const float*)d_in[5];
  const float* Wn1  = (const float*)d_in[6];
  const float* bn1  = (const float*)d_in[7];
  const float* Wx2  = (const float*)d_in[8];
  const float* bx2  = (const float*)d_in[9];
  const float* Wn2  = (const float*)d_in[10];
  const float* bn2  = (const float*)d_in[11];
  float* out = (float*)d_out;

  Perm25 p25;
  Perm10 p10;
  compute_perm(0u, S1, p25.p);
  compute_perm(1u, S2, p10.p);

  // Workspace carve-up (~55 MB).
  char* w = (char*)d_ws;
  int*            idx1 = (int*)w;            w += align256(sizeof(int) * L2ROWS);
  float*          w1   = (float*)w;          w += align256(sizeof(float) * L2ROWS);
  uint32_t*       fb   = (uint32_t*)w;       w += align256(2 * (size_t)NFEAT * DIM);
  unsigned short* M1   = (unsigned short*)w; w += align256(2 * (size_t)MROWS * DIM);
  unsigned short* Hb   = (unsigned short*)w; w += align256(2 * (size_t)MROWS * DIM);
  unsigned short* M2   = (unsigned short*)w; w += align256(2 * (size_t)BATCH * DIM);
  unsigned short* Wt1  = (unsigned short*)w; w += align256(2 * (size_t)DIM * KTOT);
  unsigned short* Wt2  = (unsigned short*)w; w += align256(2 * (size_t)DIM * KTOT);

  prep_k<<<PREP_BLOCKS, 256, 0, stream>>>(feats, fb, Wx1, Wn1, Wt1, Wx2, Wn2, Wt2,
                                          ids, dix, dval, idx1, w1, p25);
  stage1_k<<<MROWS / 4, 256, 0, stream>>>((const uint4*)fb, idx1, w1, dix, dval, p10,
                                          (uint4*)M1);
  gemm_k<true, true><<<dim3(MROWS / 64, DIM / 128), 256, 0, stream>>>(
      (const unsigned short*)fb, ids, idx1, M1, Wt1, bx1, bn1, Hb);
  stage2_k<<<BATCH / 4, 256, 0, stream>>>((const uint2*)Hb, w1, (uint2*)M2);
  gemm_k<false, false><<<dim3(BATCH / 64, DIM / 128), 256, 0, stream>>>(
      Hb, nullptr, nullptr, M2, Wt2, bx2, bn2, out);
}

// Round 5
// 178.794 us; speedup vs baseline: 1.0321x; 1.0321x over previous
//
#include <hip/hip_runtime.h>
#include <stdint.h>
#include <stddef.h>
#include <algorithm>

// Problem constants (fixed by the reference file)
#define BATCH  1024
#define S1     25
#define S2     10
#define DIM    256
#define NNEIB  64
#define L2ROWS (BATCH * S1)          // 25600
#define MROWS  (BATCH + BATCH * S1)  // 26624 (multiple of 128)
#define KTOT   512                   // GEMM K = [X | M]
#define NFEAT  50000

struct Perm25 { int p[S1]; };
struct Perm10 { int p[S2]; };

typedef __attribute__((ext_vector_type(8))) short short8;
typedef __attribute__((ext_vector_type(4))) float f32x4;

// ======================= host-side JAX threefry replication ==================
static inline uint32_t rotl_(uint32_t x, int d) { return (x << d) | (x >> (32 - d)); }

static void tf2x32(uint32_t k0, uint32_t k1, uint32_t x0, uint32_t x1,
                   uint32_t* o0, uint32_t* o1) {
  const uint32_t ks0 = k0, ks1 = k1, ks2 = k0 ^ k1 ^ 0x1BD11BDAu;
  static const int R[8] = {13, 15, 26, 6, 17, 29, 16, 24};
  x0 += ks0; x1 += ks1;
  for (int g = 0; g < 5; ++g) {
    const int* rr = R + (g & 1) * 4;
    for (int i = 0; i < 4; i++) { x0 += x1; x1 = rotl_(x1, rr[i]); x1 ^= x0; }
    uint32_t a, b;
    switch (g) {
      default:
      case 0: a = ks1; b = ks2; break;
      case 1: a = ks2; b = ks0; break;
      case 2: a = ks0; b = ks1; break;
      case 3: a = ks1; b = ks2; break;
      case 4: a = ks2; b = ks0; break;
    }
    x0 += a; x1 = x1 + b + (uint32_t)(g + 1);
  }
  *o0 = x0; *o1 = x1;
}

// jax.random.permutation(fold_in(key(42), li), 64), partitionable threefry
// (verified correct in earlier rounds).
static void compute_perm(uint32_t li, int n, int* out) {
  uint32_t k0, k1, s0, s1;
  tf2x32(0u, 42u, 0u, li, &k0, &k1);
  tf2x32(k0, k1, 0u, 1u, &s0, &s1);
  uint32_t bits[NNEIB];
  for (int i = 0; i < NNEIB; i++) {
    uint32_t a, b;
    tf2x32(s0, s1, 0u, (uint32_t)i, &a, &b);
    bits[i] = a ^ b;
  }
  int idx[NNEIB];
  for (int i = 0; i < NNEIB; i++) idx[i] = i;
  std::stable_sort(idx, idx + NNEIB, [&](int A, int B) { return bits[A] < bits[B]; });
  for (int j = 0; j < n; j++) out[j] = idx[j];
}

// ============================ device helpers =================================
__device__ __forceinline__ unsigned short f2bf(float x) {
  union { float f; uint32_t u; } v; v.f = x;
  uint32_t r = (v.u + 0x7FFFu + ((v.u >> 16) & 1u)) >> 16;   // RNE
  return (unsigned short)r;
}
__device__ __forceinline__ float bfbits2f(uint32_t lo16) {
  union { uint32_t u; float f; } v; v.u = lo16 << 16;
  return v.f;
}
// async global->LDS, 16 B per lane. GLOBAL source address is PER-LANE
// (m104/m108) -> gathers/pre-swizzles are fine; LDS dest is wave-uniform
// base + lane*16 -> LDS layout must be linear (rule #21).
__device__ __forceinline__ void gload16(const unsigned short* g, unsigned short* l) {
  __builtin_amdgcn_global_load_lds(
      (const __attribute__((address_space(1))) unsigned int*)g,
      (__attribute__((address_space(3))) unsigned int*)l, 16, 0, 0);
}

// ================================ kernels ====================================

// Fused prep: [0,12500) convf  |  [12500,13012) convw W1 | [13012,13524) convw W2
// | [13524,13528) sample1. All partitions independent.
#define PREP_CONVF   12500   // NFEAT*DIM/4/256
#define PREP_CONVW   512     // DIM*KTOT/256
#define PREP_BLOCKS  (PREP_CONVF + 2 * PREP_CONVW + 4)
__global__ __launch_bounds__(256) void prep_k(
    const float* __restrict__ feats, uint32_t* __restrict__ fb,
    const float* __restrict__ Wx1, const float* __restrict__ Wn1,
    unsigned short* __restrict__ Wt1,
    const float* __restrict__ Wx2, const float* __restrict__ Wn2,
    unsigned short* __restrict__ Wt2,
    const int* __restrict__ ids, const int* __restrict__ dix,
    const float* __restrict__ dval, int* __restrict__ idx1,
    float* __restrict__ w1, Perm25 pm) {
  int b = blockIdx.x, t = threadIdx.x;
  if (b < PREP_CONVF) {
    // feats fp32 -> packed bf16, 4 elem/thread, one 8 B store
    int i = b * 256 + t;
    f32x4 v = *(const f32x4*)&feats[(size_t)i * 4];
    uint2 o;
    o.x = f2bf(v.x) | ((uint32_t)f2bf(v.y) << 16);
    o.y = f2bf(v.z) | ((uint32_t)f2bf(v.w) << 16);
    ((uint2*)fb)[i] = o;
  } else if (b < PREP_CONVF + 2 * PREP_CONVW) {
    int wi = b - PREP_CONVF;
    const float* Wx = (wi < PREP_CONVW) ? Wx1 : Wx2;
    const float* Wn = (wi < PREP_CONVW) ? Wn1 : Wn2;
    unsigned short* Wt = (wi < PREP_CONVW) ? Wt1 : Wt2;
    int idx = (wi % PREP_CONVW) * 256 + t;
    int n = idx >> 9, k = idx & 511;
    float v = (k < DIM) ? Wx[(size_t)k * DIM + n] : Wn[(size_t)(k - DIM) * DIM + n];
    Wt[(size_t)n * KTOT + k] = f2bf(v);
  } else {
    // sample1: layer-0 neighbor sampling for the 1024 batch nodes
    int i = (b - PREP_CONVF - 2 * PREP_CONVW) * 256 + t;
    if (i >= BATCH) return;
    int nid = ids[i];
    const float* vr = dval + (size_t)nid * NNEIB;
    const int* ir = dix + (size_t)nid * NNEIB;
    float v[S1];
    float s = 0.f;
    for (int j = 0; j < S1; j++) { v[j] = vr[pm.p[j]]; s += v[j]; }
    float inv = 1.f / (s + 1e-10f);
    for (int j = 0; j < S1; j++) {
      w1[i * S1 + j] = v[j] * inv;
      idx1[i * S1 + j] = ir[pm.p[j]];
    }
  }
}

// Weighted-mean aggregation, 2 rows per load instruction: half-wave h=lane>>5
// takes rows 2p+h; each half-lane gathers 16 B (8 bf16 cols). Even/odd
// partials combined by shfl_xor(32) at the end (f32 re-association only).
template <int S>
__device__ __forceinline__ void agg_pairs(const uint4* __restrict__ fb, int nbl,
                                          float wl, int lane, float a[8]) {
  int h = lane >> 5, l5 = lane & 31;
#pragma unroll
  for (int p = 0; p < (S + 1) / 2; p++) {
    int jj = 2 * p + h;
    int nid = __shfl(nbl, (jj < S) ? jj : 0);
    float wj = (jj < S) ? __shfl(wl, jj) : 0.f;
    uint4 u = fb[(size_t)nid * 32 + l5];
    a[0] += wj * bfbits2f(u.x & 0xffffu); a[1] += wj * bfbits2f(u.x >> 16);
    a[2] += wj * bfbits2f(u.y & 0xffffu); a[3] += wj * bfbits2f(u.y >> 16);
    a[4] += wj * bfbits2f(u.z & 0xffffu); a[5] += wj * bfbits2f(u.z >> 16);
    a[6] += wj * bfbits2f(u.w & 0xffffu); a[7] += wj * bfbits2f(u.w >> 16);
  }
}

// stage1: M1[r] = weighted mean of bf16 neighbor rows (M-half ONLY; gemm1
// gathers the X-half itself via per-lane global_load_lds addresses).
// Wave-per-row, 4 rows/block, uint4 paired gathers.
__global__ __launch_bounds__(256) void stage1_k(
    const uint4* __restrict__ fb, const int* __restrict__ idx1,
    const float* __restrict__ w1, const int* __restrict__ dix,
    const float* __restrict__ dval, Perm10 pm2, uint4* __restrict__ M1) {
  int wave = threadIdx.x >> 6, lane = threadIdx.x & 63;
  int r = blockIdx.x * 4 + wave;
  float a[8] = {0.f, 0.f, 0.f, 0.f, 0.f, 0.f, 0.f, 0.f};
  if (r < BATCH) {
    int nbl = 0; float wl = 0.f;
    if (lane < S1) { nbl = idx1[r * S1 + lane]; wl = w1[r * S1 + lane]; }
    agg_pairs<S1>(fb, nbl, wl, lane, a);
  } else {
    int nx = idx1[r - BATCH];
    int nbl = 0; float vj = 0.f;
    if (lane < S2) {
      int c = pm2.p[lane];
      nbl = dix[(size_t)nx * NNEIB + c];
      vj = dval[(size_t)nx * NNEIB + c];
    }
    float tot = 0.f;
#pragma unroll
    for (int j = 0; j < S2; j++) tot += __shfl(vj, j);
    float wl = vj / (tot + 1e-10f);
    agg_pairs<S2>(fb, nbl, wl, lane, a);
  }
#pragma unroll
  for (int q = 0; q < 8; q++) a[q] += __shfl_xor(a[q], 32);
  if (lane < 32) {
    uint4 o;
    o.x = f2bf(a[0]) | ((uint32_t)f2bf(a[1]) << 16);
    o.y = f2bf(a[2]) | ((uint32_t)f2bf(a[3]) << 16);
    o.z = f2bf(a[4]) | ((uint32_t)f2bf(a[5]) << 16);
    o.w = f2bf(a[6]) | ((uint32_t)f2bf(a[7]) << 16);
    M1[(size_t)r * 32 + (lane & 31)] = o;
  }
}

// stage2: M2[i] = wmean over H rows 1024+i*25+j with w1 (M-half only; gemm2
// reads its X-half straight from Hb rows 0..1023). Wave-per-row.
__global__ __launch_bounds__(256) void stage2_k(
    const uint2* __restrict__ Hb, const float* __restrict__ w1,
    uint2* __restrict__ M2) {
  int wave = threadIdx.x >> 6, lane = threadIdx.x & 63;
  int i = blockIdx.x * 4 + wave;
  float wl = (lane < S1) ? w1[(size_t)i * S1 + lane] : 0.f;
  const uint2* hb = Hb + (size_t)(BATCH + i * S1) * 64 + lane;
  float a0 = 0.f, a1 = 0.f, a2 = 0.f, a3 = 0.f;
#pragma unroll
  for (int j = 0; j < S1; j++) {
    float wj = __shfl(wl, j);
    uint2 u = hb[(size_t)j * 64];
    a0 += wj * bfbits2f(u.x & 0xffffu);
    a1 += wj * bfbits2f(u.x >> 16);
    a2 += wj * bfbits2f(u.y & 0xffffu);
    a3 += wj * bfbits2f(u.y >> 16);
  }
  uint2 o;
  o.x = f2bf(a0) | ((uint32_t)f2bf(a1) << 16);
  o.y = f2bf(a2) | ((uint32_t)f2bf(a3) << 16);
  M2[(size_t)i * 64 + lane] = o;
}

// gemm1: Out = relu(A @ Wt^T + b), A[r] = [ fb[xrow(r)] | M1[r] ] virtual.
// TBM=64 x TBN=128, BK=64: grid 832 blocks (3.25/CU) and 8 K-steps. XOR
// chunk swizzle applied via pre-swizzled per-lane GLOBAL source + swizzled
// fragment read (LDS dest linear, rule #21): fragment ds_read_b128 is
// bank-conflict-free. Single-buffered 2-barrier loop (R4's explicit dbuf
// REGRESSED -4us: LDS 24->48KB halved blocks/CU, m99/m100 confirmed).
// K accumulation order ascending 32-windows -> bit-identical numerics.
__global__ __launch_bounds__(256, 4) void gemm1_k(
    const unsigned short* __restrict__ fb, const int* __restrict__ ids,
    const int* __restrict__ idx1, const unsigned short* __restrict__ M1,
    const unsigned short* __restrict__ Wt, const float* __restrict__ bx,
    const float* __restrict__ bn, unsigned short* __restrict__ Hb) {
  __shared__ __align__(16) unsigned short As[64][64];    // 8 KB
  __shared__ __align__(16) unsigned short Bs[128][64];   // 16 KB
  int t = threadIdx.x;
  int wave = t >> 6, lane = t & 63, quad = lane >> 4, l16 = lane & 15;
  int wm = (wave >> 1) * 32;   // 2x2 wave grid: 32-row halves
  int wn = (wave & 1) * 64;    // 64-col halves
  int row0 = blockIdx.x * 64, col0 = blockIdx.y * 128;

  f32x4 acc[2][4];
#pragma unroll
  for (int i = 0; i < 2; i++)
#pragma unroll
    for (int j = 0; j < 4; j++) acc[i][j] = (f32x4){0.f, 0.f, 0.f, 0.f};

  // staging: one gload16 = 8 rows x 64 cols (1024 B). lane l -> row l>>3,
  // 16B chunk (l&7). Source pre-swizzled: LDS pos (r,q) holds global chunk
  // q ^ (r&7) (XOR involution).
  int lrow = lane >> 3;
  int scol = (((lane & 7) ^ (lrow & 7)) << 3);   // swizzled source col (bf16)

  const unsigned short* xsA[2];
  const unsigned short* msA[2];   // pre-biased by -DIM so +k0 works
#pragma unroll
  for (int cc = 0; cc < 2; cc++) {
    int grow = row0 + (wave * 2 + cc) * 8 + lrow;
    int xr = (grow < BATCH) ? ids[grow] : idx1[grow - BATCH];
    xsA[cc] = fb + (size_t)xr * DIM + scol;
    msA[cc] = M1 + (size_t)grow * DIM + scol - DIM;
  }
  const unsigned short* bsrc[4];
#pragma unroll
  for (int cc = 0; cc < 4; cc++) {
    int brow = col0 + (wave * 4 + cc) * 8 + lrow;
    bsrc[cc] = Wt + (size_t)brow * KTOT + scol;
  }

  for (int k0 = 0; k0 < KTOT; k0 += 64) {
#pragma unroll
    for (int cc = 0; cc < 2; cc++)
      gload16(((k0 < DIM) ? xsA[cc] : msA[cc]) + k0, &As[(wave * 2 + cc) * 8][0]);
#pragma unroll
    for (int cc = 0; cc < 4; cc++)
      gload16(bsrc[cc] + k0, &Bs[(wave * 4 + cc) * 8][0]);
    __syncthreads();   // compiler emits s_waitcnt vmcnt(0) before s_barrier

    short8 af[2][2], bf8[4][2];
#pragma unroll
    for (int i = 0; i < 2; i++)
#pragma unroll
      for (int kk = 0; kk < 2; kk++)
        af[i][kk] = *(const short8*)
            &As[wm + i * 16 + l16][(((kk << 2) + quad) ^ (l16 & 7)) << 3];
#pragma unroll
    for (int j = 0; j < 4; j++)
#pragma unroll
      for (int kk = 0; kk < 2; kk++)
        bf8[j][kk] = *(const short8*)
            &Bs[wn + j * 16 + l16][(((kk << 2) + quad) ^ (l16 & 7)) << 3];
#pragma unroll
    for (int i = 0; i < 2; i++)
#pragma unroll
      for (int j = 0; j < 4; j++)
#pragma unroll
        for (int kk = 0; kk < 2; kk++)   // kk innermost: ascending-k order
          acc[i][j] = __builtin_amdgcn_mfma_f32_16x16x32_bf16(
              af[i][kk], bf8[j][kk], acc[i][j], 0, 0, 0);
    __syncthreads();
  }

  // Epilogue: bias + relu. D layout: col = l16, row = quad*4 + reg (m89/m91).
  float bias[4];
#pragma unroll
  for (int j = 0; j < 4; j++) {
    int c = col0 + wn + j * 16 + l16;
    bias[j] = bx[c] + bn[c];
  }
#pragma unroll
  for (int i = 0; i < 2; i++) {
#pragma unroll
    for (int j = 0; j < 4; j++) {
      int c = col0 + wn + j * 16 + l16;
#pragma unroll
      for (int reg = 0; reg < 4; reg++) {
        int r = row0 + wm + i * 16 + quad * 4 + reg;
        float v = fmaxf(acc[i][j][reg] + bias[j], 0.f);
        Hb[(size_t)r * DIM + c] = f2bf(v);
      }
    }
  }
}

// gemm2 (small): m97-structure 64x64 tile, BK=32, fp32 out. A = [Hb | M2].
#define BK 32
template <int TBM, int TBN>
__global__ __launch_bounds__(256) void gemm2_k(
    const unsigned short* __restrict__ Ax, const unsigned short* __restrict__ Am,
    const unsigned short* __restrict__ Wt, const float* __restrict__ bx,
    const float* __restrict__ bn, float* __restrict__ Out) {
  constexpr int MI = TBM / 32;
  constexpr int NJ = TBN / 32;
  __shared__ __align__(16) unsigned short As[TBM][BK];
  __shared__ __align__(16) unsigned short Bs[TBN][BK];
  int t = threadIdx.x;
  int wave = t >> 6, lane = t & 63, quad = lane >> 4, l16 = lane & 15;
  int wm = (wave >> 1) * (TBM / 2);
  int wn = (wave & 1) * (TBN / 2);
  int row0 = blockIdx.x * TBM, col0 = blockIdx.y * TBN;

  f32x4 acc[MI][NJ];
#pragma unroll
  for (int i = 0; i < MI; i++)
#pragma unroll
    for (int j = 0; j < NJ; j++) acc[i][j] = (f32x4){0.f, 0.f, 0.f, 0.f};

  int rl = lane >> 2;
  int cl = (lane & 3) * 8;

  const unsigned short* xsrc[TBM / 64];
  const unsigned short* msrc[TBM / 64];
#pragma unroll
  for (int c = 0; c < TBM / 64; c++) {
    int grow = row0 + c * 64 + wave * 16 + rl;
    xsrc[c] = Ax + (size_t)grow * DIM + cl;
    msrc[c] = Am + (size_t)grow * DIM + cl - DIM;
  }

  for (int k0 = 0; k0 < KTOT; k0 += BK) {
#pragma unroll
    for (int c = 0; c < TBM / 64; c++)
      gload16(((k0 < DIM) ? xsrc[c] : msrc[c]) + k0, &As[c * 64 + wave * 16][0]);
#pragma unroll
    for (int c = 0; c < TBN / 64; c++) {
      int row = c * 64 + wave * 16 + rl;
      gload16(Wt + (size_t)(col0 + row) * KTOT + k0 + cl, &Bs[c * 64 + wave * 16][0]);
    }
    __syncthreads();

    short8 af[MI], bfr[NJ];
#pragma unroll
    for (int i = 0; i < MI; i++)
      af[i] = *(const short8*)&As[wm + i * 16 + l16][quad * 8];
#pragma unroll
    for (int j = 0; j < NJ; j++)
      bfr[j] = *(const short8*)&Bs[wn + j * 16 + l16][quad * 8];
#pragma unroll
    for (int i = 0; i < MI; i++)
#pragma unroll
      for (int j = 0; j < NJ; j++)
        acc[i][j] = __builtin_amdgcn_mfma_f32_16x16x32_bf16(af[i], bfr[j], acc[i][j], 0, 0, 0);
    __syncthreads();
  }

  float bias[NJ];
#pragma unroll
  for (int j = 0; j < NJ; j++) {
    int c = col0 + wn + j * 16 + l16;
    bias[j] = bx[c] + bn[c];
  }
#pragma unroll
  for (int i = 0; i < MI; i++) {
#pragma unroll
    for (int j = 0; j < NJ; j++) {
      int c = col0 + wn + j * 16 + l16;
#pragma unroll
      for (int reg = 0; reg < 4; reg++) {
        int r = row0 + wm + i * 16 + quad * 4 + reg;
        Out[(size_t)r * DIM + c] = fmaxf(acc[i][j][reg] + bias[j], 0.f);
      }
    }
  }
}

// ================================ launcher ===================================
static inline size_t align256(size_t x) { return (x + 255) & ~(size_t)255; }

extern "C" void kernel_launch(void* const* d_in, const int* in_sizes, int n_in,
                              void* d_out, int out_size, void* d_ws, size_t ws_size,
                              hipStream_t stream) {
  const int*   ids  = (const int*)d_in[0];
  const int*   dix  = (const int*)d_in[1];
  const float* dval = (const float*)d_in[2];
  const float* feats= (const float*)d_in[3];
  const float* Wx1  = (const float*)d_in[4];
  const float* bx1  = (const float*)d_in[5];
  const float* Wn1  = (const float*)d_in[6];
  const float* bn1  = (const float*)d_in[7];
  const float* Wx2  = (const float*)d_in[8];
  const float* bx2  = (const float*)d_in[9];
  const float* Wn2  = (const float*)d_in[10];
  const float* bn2  = (const float*)d_in[11];
  float* out = (float*)d_out;

  Perm25 p25;
  Perm10 p10;
  compute_perm(0u, S1, p25.p);
  compute_perm(1u, S2, p10.p);

  // Workspace carve-up (~55 MB).
  char* w = (char*)d_ws;
  int*            idx1 = (int*)w;            w += align256(sizeof(int) * L2ROWS);
  float*          w1   = (float*)w;          w += align256(sizeof(float) * L2ROWS);
  uint32_t*       fb   = (uint32_t*)w;       w += align256(2 * (size_t)NFEAT * DIM);
  unsigned short* M1   = (unsigned short*)w; w += align256(2 * (size_t)MROWS * DIM);
  unsigned short* Hb   = (unsigned short*)w; w += align256(2 * (size_t)MROWS * DIM);
  unsigned short* M2   = (unsigned short*)w; w += align256(2 * (size_t)BATCH * DIM);
  unsigned short* Wt1  = (unsigned short*)w; w += align256(2 * (size_t)DIM * KTOT);
  unsigned short* Wt2  = (unsigned short*)w; w += align256(2 * (size_t)DIM * KTOT);

  prep_k<<<PREP_BLOCKS, 256, 0, stream>>>(feats, fb, Wx1, Wn1, Wt1, Wx2, Wn2, Wt2,
                                          ids, dix, dval, idx1, w1, p25);
  stage1_k<<<MROWS / 4, 256, 0, stream>>>((const uint4*)fb, idx1, w1, dix, dval, p10,
                                          (uint4*)M1);
  gemm1_k<<<dim3(MROWS / 64, DIM / 128), 256, 0, stream>>>(
      (const unsigned short*)fb, ids, idx1, M1, Wt1, bx1, bn1, Hb);
  stage2_k<<<BATCH / 4, 256, 0, stream>>>((const uint2*)Hb, w1, (uint2*)M2);
  gemm2_k<64, 64><<<dim3(BATCH / 64, DIM / 64), 256, 0, stream>>>(
      Hb, M2, Wt2, bx2, bn2, out);
}